// Round 18
// baseline (189.963 us; speedup 1.0000x reference)
//
#include <hip/hip_runtime.h>
#include <hip/hip_bf16.h>
#include <math.h>

// Problem constants (B=2, S=2048, D=1024, H=16, DH=64)
#define BB 2
#define SS 2048
#define DD 1024
#define HH 16
#define DH 64
#define NTOK (BB * SS)   // 4096
#define LN_EPS 1e-5f
#define BIGNEG -1e30f

typedef __attribute__((ext_vector_type(8))) short bf16x8;   // 8 bf16 = 4 VGPRs
typedef __attribute__((ext_vector_type(4))) float f32x4;    // MFMA accumulator

static __device__ __forceinline__ unsigned short f2bu(float f) {
    __hip_bfloat16 h = __float2bfloat16(f);
    return *(unsigned short*)&h;
}

// RAW v_exp_f32 (base-2). libm exp2f adds range/denormal handling (+8%
// VALUBusy measured r12); the builtin is the bare instruction. Inputs are
// <= 0 here; FTZ on tiny results is exactly what softmax wants.
static __device__ __forceinline__ float fast_exp2(float x) {
    return __builtin_amdgcn_exp2f(x);
}

// async 16B global -> LDS. LDS dest is wave-uniform base + lane*16 by construction.
static __device__ __forceinline__ void async16(const void* g, void* l) {
    __builtin_amdgcn_global_load_lds((const __attribute__((address_space(1))) void*)g,
                                     (__attribute__((address_space(3))) void*)l, 16, 0, 0);
}

// XOR-swizzle: DMA-staged LDS rows are 128B apart (bank 0 every row).
// Store chunk (row, d) at (row, d ^ (row&7)), read back at d ^ (row&7):
// b128 reads spread over all 8 4-bank groups (2-way, free).

// ---------------------------------------------------------------------------
// Merged prep: weight transpose+cast (blocks 0..10239) + LN1 (blocks 10240+).
// ---------------------------------------------------------------------------
__global__ __launch_bounds__(256) void prep_kernel(const float* __restrict__ Wq,
                                                   const float* __restrict__ Wk,
                                                   const float* __restrict__ Wv,
                                                   const float* __restrict__ Wo,
                                                   const float* __restrict__ W1,
                                                   const float* __restrict__ W2,
                                                   __hip_bfloat16* __restrict__ wqkvt,
                                                   __hip_bfloat16* __restrict__ wot,
                                                   __hip_bfloat16* __restrict__ w1t,
                                                   __hip_bfloat16* __restrict__ w2t,
                                                   const float* __restrict__ x,
                                                   const float* __restrict__ gamma,
                                                   const float* __restrict__ beta,
                                                   __hip_bfloat16* __restrict__ lnb) {
    __shared__ float t[32][33];
    __shared__ float red[256];
    const int bid = blockIdx.x;
    const int tid = threadIdx.x;

    if (bid >= 10240) {
        // ---- LayerNorm row
        const int row = bid - 10240;
        const float* xp = x + (size_t)row * DD;
        float vals[4];
        float s = 0.f;
#pragma unroll
        for (int i = 0; i < 4; ++i) {
            float v = xp[tid + i * 256];
            vals[i] = v;
            s += v;
        }
        red[tid] = s;
        __syncthreads();
        for (int st = 128; st > 0; st >>= 1) {
            if (tid < st) red[tid] += red[tid + st];
            __syncthreads();
        }
        const float mu = red[0] * (1.0f / DD);
        __syncthreads();
        float sq = 0.f;
#pragma unroll
        for (int i = 0; i < 4; ++i) {
            float d = vals[i] - mu;
            sq += d * d;
        }
        red[tid] = sq;
        __syncthreads();
        for (int st = 128; st > 0; st >>= 1) {
            if (tid < st) red[tid] += red[tid + st];
            __syncthreads();
        }
        const float rinv = rsqrtf(red[0] * (1.0f / DD) + LN_EPS);
        __hip_bfloat16* op = lnb + (size_t)row * DD;
#pragma unroll
        for (int i = 0; i < 4; ++i) {
            int j = tid + i * 256;
            op[j] = __float2bfloat16(gamma[j] * ((vals[i] - mu) * rinv) + beta[j]);
        }
        return;
    }

    // ---- weight transpose tile
    const float* W;
    __hip_bfloat16* Wt;
    int K, N, tile;
    if (bid < 4096) {
        const int m = bid >> 10;
        tile = bid & 1023;
        W = (m == 0) ? Wq : (m == 1) ? Wk : (m == 2) ? Wv : Wo;
        Wt = (m < 3) ? (wqkvt + (size_t)m * 1024 * 1024) : wot;
        K = 1024; N = 1024;
    } else if (bid < 8192) {
        tile = bid - 4096; W = W1; Wt = w1t; K = 1024; N = 4096;
    } else {
        tile = bid - 8192; W = W2; Wt = w2t; K = 2048; N = 1024;
    }
    const int nt = N >> 5;
    const int n0 = (tile % nt) * 32, k0 = (tile / nt) * 32;
    const int tx = tid & 31, ty = tid >> 5;
#pragma unroll
    for (int i = 0; i < 4; ++i)
        t[ty + 8 * i][tx] = W[(size_t)(k0 + ty + 8 * i) * N + n0 + tx];
    __syncthreads();
#pragma unroll
    for (int i = 0; i < 4; ++i)
        Wt[(size_t)(n0 + ty + 8 * i) * K + k0 + tx] = __float2bfloat16(t[tx][ty + 8 * i]);
}

// ---------------------------------------------------------------------------
// LayerNorm fp32 -> bf16 (standalone, for ln2). One block per row.
// ---------------------------------------------------------------------------
__global__ __launch_bounds__(256) void ln_kernel(const float* __restrict__ x,
                                                 const float* __restrict__ gamma,
                                                 const float* __restrict__ beta,
                                                 __hip_bfloat16* __restrict__ out) {
    const int row = blockIdx.x;
    const int tid = threadIdx.x;
    __shared__ float red[256];

    const float* xp = x + (size_t)row * DD;
    float vals[4];
    float s = 0.f;
#pragma unroll
    for (int i = 0; i < 4; ++i) {
        float v = xp[tid + i * 256];
        vals[i] = v;
        s += v;
    }
    red[tid] = s;
    __syncthreads();
    for (int st = 128; st > 0; st >>= 1) {
        if (tid < st) red[tid] += red[tid + st];
        __syncthreads();
    }
    const float mu = red[0] * (1.0f / DD);
    __syncthreads();
    float sq = 0.f;
#pragma unroll
    for (int i = 0; i < 4; ++i) {
        float d = vals[i] - mu;
        sq += d * d;
    }
    red[tid] = sq;
    __syncthreads();
    for (int st = 128; st > 0; st >>= 1) {
        if (tid < st) red[tid] += red[tid + st];
        __syncthreads();
    }
    const float rinv = rsqrtf(red[0] * (1.0f / DD) + LN_EPS);

    __hip_bfloat16* op = out + (size_t)row * DD;
#pragma unroll
    for (int i = 0; i < 4; ++i) {
        int j = tid + i * 256;
        op[j] = __float2bfloat16(gamma[j] * ((vals[i] - mu) * rinv) + beta[j]);
    }
}

// ---------------------------------------------------------------------------
// qkv GEMM, r18: 128x64 tile (the occupancy lever, 4th application).
// Old 128x128 ran 768 blocks = 3/CU at 32KB LDS (latency-starved like every
// other GEMM before its narrowing). 128x64 -> 1536 blocks = 6/CU at 24KB.
// Per wave: 32 rows x 64 cols, 16 MFMA : 6 async16 per K-step (proven n64
// structure). V columns (col0 >= 2048) write TRANSPOSED into VT (fused
// vtrans, r8). 2D XCD chunk: 4x2 groups, chunk = 8x24 tiles
// (per-XCD set A 2MB + B 3MB = 5MB).
// ---------------------------------------------------------------------------
__global__ __launch_bounds__(256) void mfma_gemm_qkv64(const __hip_bfloat16* __restrict__ A,
                                                       const __hip_bfloat16* __restrict__ Bt,
                                                       __hip_bfloat16* __restrict__ out,
                                                       __hip_bfloat16* __restrict__ vtout) {
    __shared__ short As[128 * 64];
    __shared__ short Bs[64 * 64];
    const int tid = threadIdx.x;
    const int lane = tid & 63;
    const int wave = tid >> 6;
    // 2D XCD chunk: xcd grid = 4 row-groups x 2 col-groups; chunk 8x24 tiles
    const int xcd = blockIdx.x & 7;
    const int i = blockIdx.x >> 3;                        // [0,192)
    const int row0 = ((xcd >> 1) * 8 + (i / 24)) * 128;   // 32 row-tiles
    const int col0 = ((xcd & 1) * 24 + (i % 24)) * 64;    // 48 col-tiles
    const int wr = wave * 32;
    const int l15 = lane & 15;
    const int quad = lane >> 4;
    const int s7 = l15 & 7;

    f32x4 acc[2][4] = {};

    for (int k0 = 0; k0 < 1024; k0 += 64) {
#pragma unroll
        for (int r = 0; r < 4; ++r) {
            const int ec = r * 256 + tid;
            const int ar = ec >> 3, d = ec & 7;
            const int ao = (d ^ (ar & 7)) << 3;
            async16(&A[(size_t)(row0 + ar) * 1024 + k0 + ao], &As[ec << 3]);
        }
#pragma unroll
        for (int r = 0; r < 2; ++r) {
            const int ec = r * 256 + tid;
            const int ar = ec >> 3, d = ec & 7;
            const int ao = (d ^ (ar & 7)) << 3;
            async16(&Bt[(size_t)(col0 + ar) * 1024 + k0 + ao], &Bs[ec << 3]);
        }
        __syncthreads();
#pragma unroll
        for (int kk = 0; kk < 2; ++kk) {
            const int co = (((kk << 2) | quad) ^ s7) << 3;
            bf16x8 af[2], bfr[4];
#pragma unroll
            for (int ii = 0; ii < 2; ++ii)
                af[ii] = *(const bf16x8*)&As[(wr + ii * 16 + l15) * 64 + co];
#pragma unroll
            for (int j = 0; j < 4; ++j)
                bfr[j] = *(const bf16x8*)&Bs[(j * 16 + l15) * 64 + co];
#pragma unroll
            for (int ii = 0; ii < 2; ++ii)
#pragma unroll
                for (int j = 0; j < 4; ++j)
                    acc[ii][j] = __builtin_amdgcn_mfma_f32_16x16x32_bf16(af[ii], bfr[j], acc[ii][j], 0, 0, 0);
        }
        __syncthreads();
    }

    const int r4 = quad * 4;
    if (col0 >= 2048) {
        // V columns: write transposed into VT[c][token], 8B packed (4 rows)
#pragma unroll
        for (int ii = 0; ii < 2; ++ii) {
#pragma unroll
            for (int j = 0; j < 4; ++j) {
                const int cc = col0 + j * 16 + l15 - 2048;
                const int orow0 = row0 + wr + ii * 16 + r4;
                const unsigned long long pk =
                    (unsigned long long)(((unsigned)f2bu(acc[ii][j][3]) << 16) | f2bu(acc[ii][j][2])) << 32 |
                    (((unsigned)f2bu(acc[ii][j][1]) << 16) | f2bu(acc[ii][j][0]));
                *(unsigned long long*)((unsigned short*)vtout + (size_t)cc * 4096 + orow0) = pk;
            }
        }
        return;
    }
#pragma unroll
    for (int ii = 0; ii < 2; ++ii) {
#pragma unroll
        for (int j = 0; j < 4; ++j) {
            const int orow0 = row0 + wr + ii * 16 + r4;
            const int ocol = col0 + j * 16 + l15;
#pragma unroll
            for (int rg = 0; rg < 4; ++rg)
                out[(size_t)(orow0 + rg) * 3072 + ocol] = __float2bfloat16(acc[ii][j][rg]);
        }
    }
}

// ---------------------------------------------------------------------------
// MFMA bf16 GEMM, 64x64 tile (r14 proven): for the N=1024 GEMMs (Wo, W2).
// 1024 blocks = 4/CU at 16KB LDS. Per wave: 16 rows x 64 cols,
// 8 MFMA : 4 async16 per K-step. 2D XCD chunk: 4x2 groups, 16x8 tile chunks.
// ---------------------------------------------------------------------------
template <int RES, int EPI>
__global__ __launch_bounds__(256) void mfma_gemm_n6464(const __hip_bfloat16* __restrict__ A,
                                                       const __hip_bfloat16* __restrict__ Bt,
                                                       const void* __restrict__ res,
                                                       void* __restrict__ out,
                                                       int N, int K) {
    __shared__ short As[64 * 64];
    __shared__ short Bs[64 * 64];
    const int tid = threadIdx.x;
    const int lane = tid & 63;
    const int wave = tid >> 6;
    // 2D XCD chunk: xcd grid = 4 row-groups x 2 col-groups; chunk 16x8 tiles
    const int xcd = blockIdx.x & 7;
    const int i = blockIdx.x >> 3;                        // [0,128)
    const int row0 = ((xcd >> 1) * 16 + (i >> 3)) * 64;   // 64 row-tiles
    const int col0 = ((xcd & 1) * 8 + (i & 7)) * 64;      // 16 col-tiles
    const int wr = wave * 16;
    const int l15 = lane & 15;
    const int quad = lane >> 4;
    const int s7 = l15 & 7;

    f32x4 acc[4] = {};

    for (int k0 = 0; k0 < K; k0 += 64) {
#pragma unroll
        for (int r = 0; r < 2; ++r) {
            const int ec = r * 256 + tid;
            const int ar = ec >> 3, d = ec & 7;
            const int ao = (d ^ (ar & 7)) << 3;
            async16(&A[(size_t)(row0 + ar) * K + k0 + ao], &As[ec << 3]);
            async16(&Bt[(size_t)(col0 + ar) * K + k0 + ao], &Bs[ec << 3]);
        }
        __syncthreads();
#pragma unroll
        for (int kk = 0; kk < 2; ++kk) {
            const int co = (((kk << 2) | quad) ^ s7) << 3;
            const bf16x8 af = *(const bf16x8*)&As[(wr + l15) * 64 + co];
            bf16x8 bfr[4];
#pragma unroll
            for (int j = 0; j < 4; ++j)
                bfr[j] = *(const bf16x8*)&Bs[(j * 16 + l15) * 64 + co];
#pragma unroll
            for (int j = 0; j < 4; ++j)
                acc[j] = __builtin_amdgcn_mfma_f32_16x16x32_bf16(af, bfr[j], acc[j], 0, 0, 0);
        }
        __syncthreads();
    }

    const int r4 = quad * 4;
#pragma unroll
    for (int j = 0; j < 4; ++j) {
        const int orow0 = row0 + wr + r4;
        const int ocol = col0 + j * 16 + l15;
#pragma unroll
        for (int rg = 0; rg < 4; ++rg) {
            const size_t oi = (size_t)(orow0 + rg) * N + ocol;
            float v = acc[j][rg];
            if constexpr (RES == 1) v += ((const float*)res)[oi];
            if constexpr (EPI == 0) ((float*)out)[oi] = v;
            if constexpr (EPI == 1) ((__hip_bfloat16*)out)[oi] = __float2bfloat16(v);
        }
    }
}

// ---------------------------------------------------------------------------
// Fused FFN-in GEMM+GLU, 128x64 tile (r7/r14 measured-best, 187.4us config):
// 32 MFMA/wave/K-step, 32KB LDS, 1024 blocks = 4/CU.
// 2D XCD chunk: 4x2 groups, chunk 8x16 tiles.
// ---------------------------------------------------------------------------
__global__ __launch_bounds__(256) void mfma_gemm_glu64(const __hip_bfloat16* __restrict__ A,
                                                       const __hip_bfloat16* __restrict__ Bt,
                                                       __hip_bfloat16* __restrict__ out) {
    __shared__ short As[128 * 64];
    __shared__ short Bl[64 * 64];
    __shared__ short Br[64 * 64];
    const int tid = threadIdx.x;
    const int lane = tid & 63;
    const int wave = tid >> 6;
    const int xcd = blockIdx.x & 7;
    const int i = blockIdx.x >> 3;                  // [0,128)
    const int row0 = ((xcd >> 1) * 8 + (i >> 4)) * 128;   // 32 row-tiles
    const int col0 = ((xcd & 1) * 16 + (i & 15)) * 64;    // 32 col-tiles
    const int wr = wave * 32;
    const int l15 = lane & 15;
    const int quad = lane >> 4;
    const int s7 = l15 & 7;

    f32x4 accl[2][4] = {};
    f32x4 accr[2][4] = {};

    for (int k0 = 0; k0 < 1024; k0 += 64) {
#pragma unroll
        for (int r = 0; r < 4; ++r) {
            const int ec = r * 256 + tid;
            const int ar = ec >> 3, d = ec & 7;
            const int ao = (d ^ (ar & 7)) << 3;
            async16(&A[(size_t)(row0 + ar) * 1024 + k0 + ao], &As[ec << 3]);
        }
#pragma unroll
        for (int r = 0; r < 2; ++r) {
            const int ec = r * 256 + tid;
            const int ar = ec >> 3, d = ec & 7;
            const int ao = (d ^ (ar & 7)) << 3;
            async16(&Bt[(size_t)(col0 + ar) * 1024 + k0 + ao], &Bl[ec << 3]);
            async16(&Bt[(size_t)(2048 + col0 + ar) * 1024 + k0 + ao], &Br[ec << 3]);
        }
        __syncthreads();
#pragma unroll
        for (int kk = 0; kk < 2; ++kk) {
            const int co = (((kk << 2) | quad) ^ s7) << 3;
            bf16x8 af[2], bl[4], br[4];
#pragma unroll
            for (int ii = 0; ii < 2; ++ii)
                af[ii] = *(const bf16x8*)&As[(wr + ii * 16 + l15) * 64 + co];
#pragma unroll
            for (int j = 0; j < 4; ++j) {
                bl[j] = *(const bf16x8*)&Bl[(j * 16 + l15) * 64 + co];
                br[j] = *(const bf16x8*)&Br[(j * 16 + l15) * 64 + co];
            }
#pragma unroll
            for (int ii = 0; ii < 2; ++ii)
#pragma unroll
                for (int j = 0; j < 4; ++j) {
                    accl[ii][j] = __builtin_amdgcn_mfma_f32_16x16x32_bf16(af[ii], bl[j], accl[ii][j], 0, 0, 0);
                    accr[ii][j] = __builtin_amdgcn_mfma_f32_16x16x32_bf16(af[ii], br[j], accr[ii][j], 0, 0, 0);
                }
        }
        __syncthreads();
    }

    const int r4 = quad * 4;
#pragma unroll
    for (int ii = 0; ii < 2; ++ii) {
#pragma unroll
        for (int j = 0; j < 4; ++j) {
#pragma unroll
            for (int rg = 0; rg < 4; ++rg) {
                const int orow = row0 + wr + ii * 16 + r4 + rg;
                const int ocol = col0 + j * 16 + l15;
                const float l = accl[ii][j][rg];
                const float r = accr[ii][j][rg];
                out[(size_t)orow * 2048 + ocol] =
                    __float2bfloat16(l * (1.f / (1.f + __expf(-r))));
            }
        }
    }
}

// ---------------------------------------------------------------------------
// MFMA flash attention v15 (r13/r14 proven best, 4-wave): v12 skeleton +
// log2-domain softmax via RAW __builtin_amdgcn_exp2f. Unchanged.
// ---------------------------------------------------------------------------
#define KADV (64 * 3072)
#define SCL2E 0.1803368801f   // 0.125 * log2(e)
#define RESCALE_THR2 11.54f   // 8 * log2(e)

__global__ __launch_bounds__(256, 4) void flash_mfma(const __hip_bfloat16* __restrict__ qkv_,
                                                     const __hip_bfloat16* __restrict__ VT_,
                                                     const int* __restrict__ mask,
                                                     __hip_bfloat16* __restrict__ attnb) {
    const unsigned short* qkv = (const unsigned short*)qkv_;
    const unsigned short* VT = (const unsigned short*)VT_;
    __shared__ __align__(16) short Ks[2][64 * 64];  // [buf][key][dim], swizzled
    __shared__ __align__(16) short Vt[2][64 * 64];  // [buf][dim][key], swizzled
    __shared__ __align__(16) short Ps[4][16 * 64];  // per-wave P [q][k], swizzled

    const int tid = threadIdx.x;
    const int lane = tid & 63;
    const int wave = tid >> 6;
    const int l15 = lane & 15;
    const int quad = lane >> 4;
    const int s7 = l15 & 7;

    // XCD-aware decode + balanced qt bijection (per-CU totals = 66 units)
    const int xcd = blockIdx.x & 7;
    const int slot = blockIdx.x >> 3;
    const int bh = xcd + ((slot & 3) << 3);
    const int v = slot >> 2;                 // [0,32)
    const int vr = v & 7, vs = v >> 3;       // vs in [0,4)
    const int qt = (vs == 0) ? 31 - vr : (vs == 1) ? vr : (vs == 2) ? 23 - vr : 8 + vr;
    const int h = bh & 15;
    const int b = bh >> 4;
    const int q0 = qt * 64 + wave * 16;

    // hoisted per-thread staging pointers (chunk 0) + fixed LDS dests
    const int e0 = tid, e1 = 256 + tid;
    const int r0 = e0 >> 3, d0 = e0 & 7, r1 = e1 >> 3, d1 = e1 & 7;
    const unsigned short* kp0 = qkv + (size_t)(b * SS + r0) * 3072 + 1024 + h * 64 + ((d0 ^ (r0 & 7)) << 3);
    const unsigned short* kp1 = qkv + (size_t)(b * SS + r1) * 3072 + 1024 + h * 64 + ((d1 ^ (r1 & 7)) << 3);
    const unsigned short* vp0 = VT + (size_t)(h * 64 + r0) * 4096 + b * SS + ((d0 ^ (r0 & 7)) << 3);
    const unsigned short* vp1 = VT + (size_t)(h * 64 + r1) * 4096 + b * SS + ((d1 ^ (r1 & 7)) << 3);
    short* const kd0a = &Ks[0][e0 << 3]; short* const kd0b = &Ks[1][e0 << 3];
    short* const kd1a = &Ks[0][e1 << 3]; short* const kd1b = &Ks[1][e1 << 3];
    short* const vd0a = &Vt[0][e0 << 3]; short* const vd0b = &Vt[1][e0 << 3];
    short* const vd1a = &Vt[0][e1 << 3]; short* const vd1b = &Vt[1][e1 << 3];

    const int* const mrow = mask + b * SS;

    // Q fragments (B-operand: col=q=l15, elems d=ks*32+quad*8..)
    bf16x8 aq[2];
#pragma unroll
    for (int ks = 0; ks < 2; ++ks)
        aq[ks] = *(const bf16x8*)(qkv + (size_t)(b * SS + q0 + l15) * 3072 +
                                  h * 64 + ks * 32 + quad * 8);

    // O^T accumulators: [d-tile nt][rg]: d = nt*16+quad*4+rg, q = q0+l15
    f32x4 O[4];
#pragma unroll
    for (int i = 0; i < 4; ++i) O[i] = (f32x4){0.f, 0.f, 0.f, 0.f};
    float m_r = BIGNEG, l_r = 0.f;   // per-lane scalars, log2 domain

    short* const Pw = &Ps[wave][0];

    // stage chunk 0 into buffer 0; advance pointers to chunk 1
    async16(kp0, kd0a); async16(kp1, kd1a);
    async16(vp0, vd0a); async16(vp1, vd1a);
    kp0 += KADV; kp1 += KADV; vp0 += 64; vp1 += 64;

    // ======== FULL chunks 0..qt-1 (ktmax=ktfull=4 for every wave) ========
    for (int c = 0; c < qt; ++c) {
        const int cur = c & 1;
        __syncthreads();   // drains chunk-c DMA + chunk-(c-1) LDS reads

        // prefetch chunk c+1 into the other buffer (c+1 <= qt always valid)
        async16(kp0, cur ? kd0a : kd0b);
        async16(kp1, cur ? kd1a : kd1b);
        async16(vp0, cur ? vd0a : vd0b);
        async16(vp1, cur ? vd1a : vd1b);
        kp0 += KADV; kp1 += KADV; vp0 += 64; vp1 += 64;

        const int kb = c << 6;
        const short* Kc = &Ks[cur][0];
        const short* Vc = &Vt[cur][0];

        int4 mv[4];
#pragma unroll
        for (int kt = 0; kt < 4; ++kt)
            mv[kt] = *(const int4*)&mrow[kb + kt * 16 + quad * 4];

        // ---- S^T = K Q^T, straight-line
        f32x4 S[4];
        __builtin_amdgcn_s_setprio(1);
#pragma unroll
        for (int kt = 0; kt < 4; ++kt) {
            const bf16x8 bk0 = *(const bf16x8*)&Kc[(kt * 16 + l15) * 64 + ((quad ^ s7) << 3)];
            const bf16x8 bk1 = *(const bf16x8*)&Kc[(kt * 16 + l15) * 64 + (((4 | quad) ^ s7) << 3)];
            f32x4 z = {0.f, 0.f, 0.f, 0.f};
            z = __builtin_amdgcn_mfma_f32_16x16x32_bf16(bk0, aq[0], z, 0, 0, 0);
            S[kt] = __builtin_amdgcn_mfma_f32_16x16x32_bf16(bk1, aq[1], z, 0, 0, 0);
        }
        __builtin_amdgcn_s_setprio(0);

        // ---- scale (log2 domain) + mask-bias (no causal below the diagonal)
#pragma unroll
        for (int kt = 0; kt < 4; ++kt) {
            const int* mm = (const int*)&mv[kt];
#pragma unroll
            for (int rg = 0; rg < 4; ++rg)
                S[kt][rg] = fmaf(S[kt][rg], SCL2E, mm[rg] ? 0.f : BIGNEG);
        }

        // ---- row max: in-lane tree (16) + cross-quad shfl(16,32)
        const float t0 = fmaxf(fmaxf(S[0][0], S[0][1]), fmaxf(S[0][2], S[0][3]));
        const float t1 = fmaxf(fmaxf(S[1][0], S[1][1]), fmaxf(S[1][2], S[1][3]));
        const float t2 = fmaxf(fmaxf(S[2][0], S[2][1]), fmaxf(S[2][2], S[2][3]));
        const float t3 = fmaxf(fmaxf(S[3][0], S[3][1]), fmaxf(S[3][2], S[3][3]));
        float tmax = fmaxf(fmaxf(t0, t1), fmaxf(t2, t3));
        tmax = fmaxf(tmax, __shfl_xor(tmax, 16));
        tmax = fmaxf(tmax, __shfl_xor(tmax, 32));

        // T13 defer-max (log2 domain)
        if (__any(tmax > m_r + RESCALE_THR2)) {
            const float mn = fmaxf(m_r, tmax);
            const float alpha = fast_exp2(m_r - mn);
            m_r = mn;
            l_r *= alpha;
#pragma unroll
            for (int nt = 0; nt < 4; ++nt)
#pragma unroll
                for (int rg = 0; rg < 4; ++rg)
                    O[nt][rg] *= alpha;
        }

        // ---- P = exp2(S - m), row-sum, pack to b64
        float rsum = 0.f;
        unsigned long long p64[4];
#pragma unroll
        for (int kt = 0; kt < 4; ++kt) {
#pragma unroll
            for (int rg = 0; rg < 4; ++rg)
                S[kt][rg] = fast_exp2(S[kt][rg] - m_r);
            rsum += (S[kt][0] + S[kt][1]) + (S[kt][2] + S[kt][3]);
            p64[kt] = ((unsigned long long)(((unsigned)f2bu(S[kt][3]) << 16) | f2bu(S[kt][2])) << 32)
                    | (((unsigned)f2bu(S[kt][1]) << 16) | f2bu(S[kt][0]));
        }
        rsum += __shfl_xor(rsum, 16);
        rsum += __shfl_xor(rsum, 32);
        l_r += rsum;

        // ---- P -> LDS: 4x ds_write_b64 (all 32 banks, balanced)
#pragma unroll
        for (int kt = 0; kt < 4; ++kt) {
            const int ch = (kt << 1) | (quad >> 1);
            const int base = (l15 << 6) + ((ch ^ s7) << 3) + ((quad & 1) << 2);
            *(unsigned long long*)&Pw[base] = p64[kt];
        }

        // ---- O^T += V_frag * P_frag
        __builtin_amdgcn_s_setprio(1);
#pragma unroll
        for (int kk = 0; kk < 2; ++kk) {
            const int co = ((((kk << 2) | quad) ^ s7) << 3);
            const bf16x8 bp = *(const bf16x8*)&Pw[(l15 << 6) + co];
#pragma unroll
            for (int nt = 0; nt < 4; ++nt) {
                const bf16x8 av = *(const bf16x8*)&Vc[(nt * 16 + l15) * 64 + co];
                O[nt] = __builtin_amdgcn_mfma_f32_16x16x32_bf16(av, bp, O[nt], 0, 0, 0);
            }
        }
        __builtin_amdgcn_s_setprio(0);
    }

    // ======== DIAGONAL chunk c = qt (dynamic per-wave extent) ========
    {
        const int cur = qt & 1;
        __syncthreads();

        const int kb = qt << 6;
        const int ktmax = wave + 1;     // dq = wave*16
        const int ktfull = wave;        // only tile kt==wave is partial
        const short* Kc = &Ks[cur][0];
        const short* Vc = &Vt[cur][0];
        const int qrow = q0 + l15;

        int4 mv[4];
#pragma unroll
        for (int kt = 0; kt < 4; ++kt) {
            if (kt >= ktmax) break;
            mv[kt] = *(const int4*)&mrow[kb + kt * 16 + quad * 4];
        }

        f32x4 S[4];
        __builtin_amdgcn_s_setprio(1);
#pragma unroll
        for (int kt = 0; kt < 4; ++kt) {
            if (kt >= ktmax) break;
            const bf16x8 bk0 = *(const bf16x8*)&Kc[(kt * 16 + l15) * 64 + ((quad ^ s7) << 3)];
            const bf16x8 bk1 = *(const bf16x8*)&Kc[(kt * 16 + l15) * 64 + (((4 | quad) ^ s7) << 3)];
            f32x4 z = {0.f, 0.f, 0.f, 0.f};
            z = __builtin_amdgcn_mfma_f32_16x16x32_bf16(bk0, aq[0], z, 0, 0, 0);
            S[kt] = __builtin_amdgcn_mfma_f32_16x16x32_bf16(bk1, aq[1], z, 0, 0, 0);
        }
        __builtin_amdgcn_s_setprio(0);

#pragma unroll
        for (int kt = 0; kt < 4; ++kt) {
            if (kt >= ktmax) break;
            const int* mm = (const int*)&mv[kt];
#pragma unroll
            for (int rg = 0; rg < 4; ++rg) {
                float s = fmaf(S[kt][rg], SCL2E, mm[rg] ? 0.f : BIGNEG);
                if (kt >= ktfull) {
                    const int key = kb + kt * 16 + quad * 4 + rg;
                    s = (key <= qrow) ? s : BIGNEG;
                }
                S[kt][rg] = s;
            }
        }

        float tmax = BIGNEG;
#pragma unroll
        for (int kt = 0; kt < 4; ++kt) {
            if (kt >= ktmax) break;
            tmax = fmaxf(tmax, fmaxf(fmaxf(S[kt][0], S[kt][1]),
                                     fmaxf(S[kt][2], S[kt][3])));
        }
        tmax = fmaxf(tmax, __shfl_xor(tmax, 16));
        tmax = fmaxf(tmax, __shfl_xor(tmax, 32));

        if (__any(tmax > m_r + RESCALE_THR2)) {
            const float mn = fmaxf(m_r, tmax);
            const float alpha = fast_exp2(m_r - mn);
            m_r = mn;
            l_r *= alpha;
#pragma unroll
            for (int nt = 0; nt < 4; ++nt)
#pragma unroll
                for (int rg = 0; rg < 4; ++rg)
                    O[nt][rg] *= alpha;
        }

        float rsum = 0.f;
#pragma unroll
        for (int kt = 0; kt < 4; ++kt) {
            if (kt >= ktmax) break;
#pragma unroll
            for (int rg = 0; rg < 4; ++rg)
                S[kt][rg] = fast_exp2(S[kt][rg] - m_r);
            rsum += (S[kt][0] + S[kt][1]) + (S[kt][2] + S[kt][3]);
            const int ch = (kt << 1) | (quad >> 1);
            const int base = (l15 << 6) + ((ch ^ s7) << 3) + ((quad & 1) << 2);
            *(unsigned long long*)&Pw[base] =
                ((unsigned long long)(((unsigned)f2bu(S[kt][3]) << 16) | f2bu(S[kt][2])) << 32)
                | (((unsigned)f2bu(S[kt][1]) << 16) | f2bu(S[kt][0]));
        }
        rsum += __shfl_xor(rsum, 16);
        rsum += __shfl_xor(rsum, 32);
        l_r += rsum;

        const int kkmax = (ktmax + 1) >> 1;
        if (ktmax & 1) {   // zero-fill phantom tile
            const int ch = (ktmax << 1) | (quad >> 1);
            const int base = (l15 << 6) + ((ch ^ s7) << 3) + ((quad & 1) << 2);
            *(unsigned long long*)&Pw[base] = 0ull;
        }

        __builtin_amdgcn_s_setprio(1);
#pragma unroll
        for (int kk = 0; kk < 2; ++kk) {
            if (kk >= kkmax) break;
            const int co = ((((kk << 2) | quad) ^ s7) << 3);
            const bf16x8 bp = *(const bf16x8*)&Pw[(l15 << 6) + co];
#pragma unroll
            for (int nt = 0; nt < 4; ++nt) {
                const bf16x8 av = *(const bf16x8*)&Vc[(nt * 16 + l15) * 64 + co];
                O[nt] = __builtin_amdgcn_mfma_f32_16x16x32_bf16(av, bp, O[nt], 0, 0, 0);
            }
        }
        __builtin_amdgcn_s_setprio(0);
    }

    // epilogue: O^T /= l, write bf16. Lane owns row q = q0+l15,
    // d = nt*16 + quad*4 + rg -> 4x 8-byte stores.
    const float inv = 1.f / l_r;
    unsigned short* op = (unsigned short*)attnb +
                         (size_t)(b * SS + q0 + l15) * 1024 + h * 64 + quad * 4;
#pragma unroll
    for (int nt = 0; nt < 4; ++nt) {
        const float o0 = O[nt][0] * inv, o1 = O[nt][1] * inv;
        const float o2 = O[nt][2] * inv, o3 = O[nt][3] * inv;
        const unsigned long long pk =
            (unsigned long long)(((unsigned)f2bu(o3) << 16) | f2bu(o2)) << 32 |
            (((unsigned)f2bu(o1) << 16) | f2bu(o0));
        *(unsigned long long*)(op + nt * 16) = pk;
    }
}

// ---------------------------------------------------------------------------
// Launch. Workspace plan (84 MB peak), bytes:
//   [0,6M)   Wqkv_t bf16 [3072][1024]
//   [6,8M)   Wo_t   bf16 [1024][1024]
//   [8,16M)  W1_t   bf16 [4096][1024]  (plain transposed)
//   [16,20M) W2_t   bf16 [1024][2048]
//   [20,28M) lnb    bf16 (ln1 then ln2)
//   [28,52M) qkvb   bf16 [4096][3072]  (V cols unwritten) -> dead after flash
//   [28,44M) x1     fp32 (reuses qkvb head)
//   [52,60M) attnb  bf16               -> dead after Wo gemm
//   [60,68M) VT     bf16 [1024][4096]  (written by qkv GEMM) -> dead after flash
//   [68,84M) glub   bf16 [4096][2048]
// ---------------------------------------------------------------------------
extern "C" void kernel_launch(void* const* d_in, const int* in_sizes, int n_in,
                              void* d_out, int out_size, void* d_ws, size_t ws_size,
                              hipStream_t stream) {
    const float* x  = (const float*)d_in[0];
    const int* mask = (const int*)d_in[1];
    const float* Wq = (const float*)d_in[2];
    const float* Wk = (const float*)d_in[3];
    const float* Wv = (const float*)d_in[4];
    const float* Wo = (const float*)d_in[5];
    const float* W1 = (const float*)d_in[6];
    const float* W2 = (const float*)d_in[7];
    const float* g1 = (const float*)d_in[8];
    const float* b1 = (const float*)d_in[9];
    const float* g2 = (const float*)d_in[10];
    const float* b2 = (const float*)d_in[11];

    const size_t MB = 1024 * 1024;
    uint8_t* ws = (uint8_t*)d_ws;
    __hip_bfloat16* wqkvt = (__hip_bfloat16*)(ws);
    __hip_bfloat16* wot   = (__hip_bfloat16*)(ws + 6 * MB);
    __hip_bfloat16* w1t   = (__hip_bfloat16*)(ws + 8 * MB);
    __hip_bfloat16* w2t   = (__hip_bfloat16*)(ws + 16 * MB);
    __hip_bfloat16* lnb   = (__hip_bfloat16*)(ws + 20 * MB);
    __hip_bfloat16* qkvb  = (__hip_bfloat16*)(ws + 28 * MB);
    float*          x1    = (float*)(ws + 28 * MB);
    __hip_bfloat16* attnb = (__hip_bfloat16*)(ws + 52 * MB);
    __hip_bfloat16* VT    = (__hip_bfloat16*)(ws + 60 * MB);
    __hip_bfloat16* glub  = (__hip_bfloat16*)(ws + 68 * MB);

    // 0. weight transposes + ln1 in one launch
    prep_kernel<<<10240 + NTOK, 256, 0, stream>>>(Wq, Wk, Wv, Wo, W1, W2,
                                                  wqkvt, wot, w1t, w2t,
                                                  x, g1, b1, lnb);

    // 1. qkv = ln1 @ [Wq|Wk|Wv]. Q,K -> qkvb rows; V cols -> VT transposed.
    //    [128x64 tiles, 1536 blocks = 6/CU at 24KB LDS]
    mfma_gemm_qkv64<<<1536, 256, 0, stream>>>(lnb, wqkvt, qkvb, VT);

    // 2. MFMA flash attention -> attnb  [4-wave, 1024 blocks = 4/CU]
    flash_mfma<<<1024, 256, 0, stream>>>(qkvb, VT, mask, attnb);

    // 3. x1 = x + attn @ Wo -> x1 (fp32)  [64x64, 1024 blocks = 4/CU]
    mfma_gemm_n6464<1, 0><<<1024, 256, 0, stream>>>(attnb, wot, x, x1, 1024, 1024);

    // 4. ln2 = LN(x1) -> lnb
    ln_kernel<<<NTOK, 256, 0, stream>>>(x1, g2, b2, lnb);

    // 5. glu = (ln2@W1L) * sigmoid(ln2@W1R) -> glub
    //    [128x64, 1024 blocks = 4/CU, 2D XCD chunks of 8 rows x 16 cols]
    mfma_gemm_glu64<<<1024, 256, 0, stream>>>(lnb, w1t, glub);

    // 6. out = x1 + glu @ W2 -> d_out (fp32)  [64x64, 1024 blocks = 4/CU]
    mfma_gemm_n6464<1, 0><<<1024, 256, 0, stream>>>(glub, w2t, x1, (float*)d_out,
                                                    1024, 2048);
}

// Round 19
// 187.184 us; speedup vs baseline: 1.0148x; 1.0148x over previous
//
#include <hip/hip_runtime.h>
#include <hip/hip_bf16.h>
#include <math.h>

// Problem constants (B=2, S=2048, D=1024, H=16, DH=64)
#define BB 2
#define SS 2048
#define DD 1024
#define HH 16
#define DH 64
#define NTOK (BB * SS)   // 4096
#define LN_EPS 1e-5f
#define BIGNEG -1e30f

typedef __attribute__((ext_vector_type(8))) short bf16x8;   // 8 bf16 = 4 VGPRs
typedef __attribute__((ext_vector_type(4))) float f32x4;    // MFMA accumulator

static __device__ __forceinline__ unsigned short f2bu(float f) {
    __hip_bfloat16 h = __float2bfloat16(f);
    return *(unsigned short*)&h;
}

// RAW v_exp_f32 (base-2). libm exp2f adds range/denormal handling (+8%
// VALUBusy measured r12); the builtin is the bare instruction. Inputs are
// <= 0 here; FTZ on tiny results is exactly what softmax wants.
static __device__ __forceinline__ float fast_exp2(float x) {
    return __builtin_amdgcn_exp2f(x);
}

// async 16B global -> LDS. LDS dest is wave-uniform base + lane*16 by construction.
static __device__ __forceinline__ void async16(const void* g, void* l) {
    __builtin_amdgcn_global_load_lds((const __attribute__((address_space(1))) void*)g,
                                     (__attribute__((address_space(3))) void*)l, 16, 0, 0);
}

// XOR-swizzle: DMA-staged LDS rows are 128B apart (bank 0 every row).
// Store chunk (row, d) at (row, d ^ (row&7)), read back at d ^ (row&7):
// b128 reads spread over all 8 4-bank groups (2-way, free).

// ---------------------------------------------------------------------------
// Merged prep: weight transpose+cast (blocks 0..10239) + LN1 (blocks 10240+).
// ---------------------------------------------------------------------------
__global__ __launch_bounds__(256) void prep_kernel(const float* __restrict__ Wq,
                                                   const float* __restrict__ Wk,
                                                   const float* __restrict__ Wv,
                                                   const float* __restrict__ Wo,
                                                   const float* __restrict__ W1,
                                                   const float* __restrict__ W2,
                                                   __hip_bfloat16* __restrict__ wqkvt,
                                                   __hip_bfloat16* __restrict__ wot,
                                                   __hip_bfloat16* __restrict__ w1t,
                                                   __hip_bfloat16* __restrict__ w2t,
                                                   const float* __restrict__ x,
                                                   const float* __restrict__ gamma,
                                                   const float* __restrict__ beta,
                                                   __hip_bfloat16* __restrict__ lnb) {
    __shared__ float t[32][33];
    __shared__ float red[256];
    const int bid = blockIdx.x;
    const int tid = threadIdx.x;

    if (bid >= 10240) {
        // ---- LayerNorm row
        const int row = bid - 10240;
        const float* xp = x + (size_t)row * DD;
        float vals[4];
        float s = 0.f;
#pragma unroll
        for (int i = 0; i < 4; ++i) {
            float v = xp[tid + i * 256];
            vals[i] = v;
            s += v;
        }
        red[tid] = s;
        __syncthreads();
        for (int st = 128; st > 0; st >>= 1) {
            if (tid < st) red[tid] += red[tid + st];
            __syncthreads();
        }
        const float mu = red[0] * (1.0f / DD);
        __syncthreads();
        float sq = 0.f;
#pragma unroll
        for (int i = 0; i < 4; ++i) {
            float d = vals[i] - mu;
            sq += d * d;
        }
        red[tid] = sq;
        __syncthreads();
        for (int st = 128; st > 0; st >>= 1) {
            if (tid < st) red[tid] += red[tid + st];
            __syncthreads();
        }
        const float rinv = rsqrtf(red[0] * (1.0f / DD) + LN_EPS);
        __hip_bfloat16* op = lnb + (size_t)row * DD;
#pragma unroll
        for (int i = 0; i < 4; ++i) {
            int j = tid + i * 256;
            op[j] = __float2bfloat16(gamma[j] * ((vals[i] - mu) * rinv) + beta[j]);
        }
        return;
    }

    // ---- weight transpose tile
    const float* W;
    __hip_bfloat16* Wt;
    int K, N, tile;
    if (bid < 4096) {
        const int m = bid >> 10;
        tile = bid & 1023;
        W = (m == 0) ? Wq : (m == 1) ? Wk : (m == 2) ? Wv : Wo;
        Wt = (m < 3) ? (wqkvt + (size_t)m * 1024 * 1024) : wot;
        K = 1024; N = 1024;
    } else if (bid < 8192) {
        tile = bid - 4096; W = W1; Wt = w1t; K = 1024; N = 4096;
    } else {
        tile = bid - 8192; W = W2; Wt = w2t; K = 2048; N = 1024;
    }
    const int nt = N >> 5;
    const int n0 = (tile % nt) * 32, k0 = (tile / nt) * 32;
    const int tx = tid & 31, ty = tid >> 5;
#pragma unroll
    for (int i = 0; i < 4; ++i)
        t[ty + 8 * i][tx] = W[(size_t)(k0 + ty + 8 * i) * N + n0 + tx];
    __syncthreads();
#pragma unroll
    for (int i = 0; i < 4; ++i)
        Wt[(size_t)(n0 + ty + 8 * i) * K + k0 + tx] = __float2bfloat16(t[tx][ty + 8 * i]);
}

// ---------------------------------------------------------------------------
// LayerNorm fp32 -> bf16 (standalone, for ln2). One block per row.
// ---------------------------------------------------------------------------
__global__ __launch_bounds__(256) void ln_kernel(const float* __restrict__ x,
                                                 const float* __restrict__ gamma,
                                                 const float* __restrict__ beta,
                                                 __hip_bfloat16* __restrict__ out) {
    const int row = blockIdx.x;
    const int tid = threadIdx.x;
    __shared__ float red[256];

    const float* xp = x + (size_t)row * DD;
    float vals[4];
    float s = 0.f;
#pragma unroll
    for (int i = 0; i < 4; ++i) {
        float v = xp[tid + i * 256];
        vals[i] = v;
        s += v;
    }
    red[tid] = s;
    __syncthreads();
    for (int st = 128; st > 0; st >>= 1) {
        if (tid < st) red[tid] += red[tid + st];
        __syncthreads();
    }
    const float mu = red[0] * (1.0f / DD);
    __syncthreads();
    float sq = 0.f;
#pragma unroll
    for (int i = 0; i < 4; ++i) {
        float d = vals[i] - mu;
        sq += d * d;
    }
    red[tid] = sq;
    __syncthreads();
    for (int st = 128; st > 0; st >>= 1) {
        if (tid < st) red[tid] += red[tid + st];
        __syncthreads();
    }
    const float rinv = rsqrtf(red[0] * (1.0f / DD) + LN_EPS);

    __hip_bfloat16* op = out + (size_t)row * DD;
#pragma unroll
    for (int i = 0; i < 4; ++i) {
        int j = tid + i * 256;
        op[j] = __float2bfloat16(gamma[j] * ((vals[i] - mu) * rinv) + beta[j]);
    }
}

// ---------------------------------------------------------------------------
// MFMA bf16 GEMM (m97 structure + XOR-swizzled LDS staging).
// C[M,N] = A[M,K] @ Bt[N,K]^T. 128x128 tile, 4 waves, BK=64.
// RES: 0 none, 1 add fp32 res[oi].  EPI: 0 fp32 out, 1 bf16 out.
// 1D grid + 2D XCD-chunked decode (r7).
// r8: optional vtout — V-column blocks write transposed into VT directly.
// ---------------------------------------------------------------------------
template <int RES, int EPI>
__global__ __launch_bounds__(256) void mfma_gemm(const __hip_bfloat16* __restrict__ A,
                                                 const __hip_bfloat16* __restrict__ Bt,
                                                 const void* __restrict__ res,
                                                 void* __restrict__ out,
                                                 int M, int N, int K,
                                                 int xcdCols, int colGroups,
                                                 __hip_bfloat16* __restrict__ vtout) {
    __shared__ short As[128 * 64];
    __shared__ short Bs[128 * 64];
    const int tid = threadIdx.x;
    const int lane = tid & 63;
    const int wave = tid >> 6;
    // 2D XCD chunk decode: xcd grid = (8/colGroups) row-groups x colGroups
    const int xcd = blockIdx.x & 7;
    const int i = blockIdx.x >> 3;
    const int xcdRows = (gridDim.x >> 3) / xcdCols;
    const int r = i / xcdCols;
    const int c = i - r * xcdCols;
    const int rowg = xcd / colGroups;
    const int colg = xcd - rowg * colGroups;
    const int row0 = (rowg * xcdRows + r) * 128;
    const int col0 = (colg * xcdCols + c) * 128;
    const int wr = (wave >> 1) * 64;
    const int wc = (wave & 1) * 64;
    const int l15 = lane & 15;
    const int quad = lane >> 4;
    const int s7 = l15 & 7;

    f32x4 acc[4][4] = {};

    for (int k0 = 0; k0 < K; k0 += 64) {
#pragma unroll
        for (int rr = 0; rr < 4; ++rr) {
            const int ec = rr * 256 + tid;
            const int ar = ec >> 3, d = ec & 7;
            const int ao = (d ^ (ar & 7)) << 3;     // swizzled source dim offset
            async16(&A[(size_t)(row0 + ar) * K + k0 + ao], &As[ec << 3]);
            async16(&Bt[(size_t)(col0 + ar) * K + k0 + ao], &Bs[ec << 3]);
        }
        __syncthreads();
#pragma unroll
        for (int kk = 0; kk < 2; ++kk) {
            const int co = (((kk << 2) | quad) ^ s7) << 3;  // swizzled chunk offset
            bf16x8 af[4], bfr[4];
#pragma unroll
            for (int ii = 0; ii < 4; ++ii)
                af[ii] = *(const bf16x8*)&As[(wr + ii * 16 + l15) * 64 + co];
#pragma unroll
            for (int j = 0; j < 4; ++j)
                bfr[j] = *(const bf16x8*)&Bs[(wc + j * 16 + l15) * 64 + co];
#pragma unroll
            for (int ii = 0; ii < 4; ++ii)
#pragma unroll
                for (int j = 0; j < 4; ++j)
                    acc[ii][j] = __builtin_amdgcn_mfma_f32_16x16x32_bf16(af[ii], bfr[j], acc[ii][j], 0, 0, 0);
        }
        __syncthreads();
    }

    const int r4 = quad * 4;
    if (vtout != nullptr && col0 >= 2048) {
        // V columns: write transposed into VT[c][token], 8B packed (4 rows)
#pragma unroll
        for (int ii = 0; ii < 4; ++ii) {
#pragma unroll
            for (int j = 0; j < 4; ++j) {
                const int cc = col0 + wc + j * 16 + l15 - 2048;
                const int orow0 = row0 + wr + ii * 16 + r4;
                const unsigned long long pk =
                    (unsigned long long)(((unsigned)f2bu(acc[ii][j][3]) << 16) | f2bu(acc[ii][j][2])) << 32 |
                    (((unsigned)f2bu(acc[ii][j][1]) << 16) | f2bu(acc[ii][j][0]));
                *(unsigned long long*)((unsigned short*)vtout + (size_t)cc * 4096 + orow0) = pk;
            }
        }
        return;
    }
#pragma unroll
    for (int ii = 0; ii < 4; ++ii) {
#pragma unroll
        for (int j = 0; j < 4; ++j) {
            const int orow0 = row0 + wr + ii * 16 + r4;
            const int ocol = col0 + wc + j * 16 + l15;
#pragma unroll
            for (int rg = 0; rg < 4; ++rg) {
                const size_t oi = (size_t)(orow0 + rg) * N + ocol;
                float v = acc[ii][j][rg];
                if constexpr (RES == 1) v += ((const float*)res)[oi];
                if constexpr (EPI == 0) ((float*)out)[oi] = v;
                if constexpr (EPI == 1) ((__hip_bfloat16*)out)[oi] = __float2bfloat16(v);
            }
        }
    }
}

// ---------------------------------------------------------------------------
// MFMA bf16 GEMM, 64x64 tile (r14 proven): for the N=1024 GEMMs (Wo, W2).
// 1024 blocks = 4/CU at 16KB LDS. Per wave: 16 rows x 64 cols,
// 8 MFMA : 4 async16 per K-step. 2D XCD chunk: 4x2 groups, 16x8 tile chunks.
// ---------------------------------------------------------------------------
template <int RES, int EPI>
__global__ __launch_bounds__(256) void mfma_gemm_n6464(const __hip_bfloat16* __restrict__ A,
                                                       const __hip_bfloat16* __restrict__ Bt,
                                                       const void* __restrict__ res,
                                                       void* __restrict__ out,
                                                       int N, int K) {
    __shared__ short As[64 * 64];
    __shared__ short Bs[64 * 64];
    const int tid = threadIdx.x;
    const int lane = tid & 63;
    const int wave = tid >> 6;
    // 2D XCD chunk: xcd grid = 4 row-groups x 2 col-groups; chunk 16x8 tiles
    const int xcd = blockIdx.x & 7;
    const int i = blockIdx.x >> 3;                        // [0,128)
    const int row0 = ((xcd >> 1) * 16 + (i >> 3)) * 64;   // 64 row-tiles
    const int col0 = ((xcd & 1) * 8 + (i & 7)) * 64;      // 16 col-tiles
    const int wr = wave * 16;
    const int l15 = lane & 15;
    const int quad = lane >> 4;
    const int s7 = l15 & 7;

    f32x4 acc[4] = {};

    for (int k0 = 0; k0 < K; k0 += 64) {
#pragma unroll
        for (int r = 0; r < 2; ++r) {
            const int ec = r * 256 + tid;
            const int ar = ec >> 3, d = ec & 7;
            const int ao = (d ^ (ar & 7)) << 3;
            async16(&A[(size_t)(row0 + ar) * K + k0 + ao], &As[ec << 3]);
            async16(&Bt[(size_t)(col0 + ar) * K + k0 + ao], &Bs[ec << 3]);
        }
        __syncthreads();
#pragma unroll
        for (int kk = 0; kk < 2; ++kk) {
            const int co = (((kk << 2) | quad) ^ s7) << 3;
            const bf16x8 af = *(const bf16x8*)&As[(wr + l15) * 64 + co];
            bf16x8 bfr[4];
#pragma unroll
            for (int j = 0; j < 4; ++j)
                bfr[j] = *(const bf16x8*)&Bs[(j * 16 + l15) * 64 + co];
#pragma unroll
            for (int j = 0; j < 4; ++j)
                acc[j] = __builtin_amdgcn_mfma_f32_16x16x32_bf16(af, bfr[j], acc[j], 0, 0, 0);
        }
        __syncthreads();
    }

    const int r4 = quad * 4;
#pragma unroll
    for (int j = 0; j < 4; ++j) {
        const int orow0 = row0 + wr + r4;
        const int ocol = col0 + j * 16 + l15;
#pragma unroll
        for (int rg = 0; rg < 4; ++rg) {
            const size_t oi = (size_t)(orow0 + rg) * N + ocol;
            float v = acc[j][rg];
            if constexpr (RES == 1) v += ((const float*)res)[oi];
            if constexpr (EPI == 0) ((float*)out)[oi] = v;
            if constexpr (EPI == 1) ((__hip_bfloat16*)out)[oi] = __float2bfloat16(v);
        }
    }
}

// ---------------------------------------------------------------------------
// Fused FFN-in GEMM+GLU, 128x64 tile (r7/r14 measured-best, 187.4us config):
// 32 MFMA/wave/K-step, 32KB LDS, 1024 blocks = 4/CU.
// 2D XCD chunk: 4x2 groups, chunk 8x16 tiles.
// ---------------------------------------------------------------------------
__global__ __launch_bounds__(256) void mfma_gemm_glu64(const __hip_bfloat16* __restrict__ A,
                                                       const __hip_bfloat16* __restrict__ Bt,
                                                       __hip_bfloat16* __restrict__ out) {
    __shared__ short As[128 * 64];
    __shared__ short Bl[64 * 64];
    __shared__ short Br[64 * 64];
    const int tid = threadIdx.x;
    const int lane = tid & 63;
    const int wave = tid >> 6;
    const int xcd = blockIdx.x & 7;
    const int i = blockIdx.x >> 3;                  // [0,128)
    const int row0 = ((xcd >> 1) * 8 + (i >> 4)) * 128;   // 32 row-tiles
    const int col0 = ((xcd & 1) * 16 + (i & 15)) * 64;    // 32 col-tiles
    const int wr = wave * 32;
    const int l15 = lane & 15;
    const int quad = lane >> 4;
    const int s7 = l15 & 7;

    f32x4 accl[2][4] = {};
    f32x4 accr[2][4] = {};

    for (int k0 = 0; k0 < 1024; k0 += 64) {
#pragma unroll
        for (int r = 0; r < 4; ++r) {
            const int ec = r * 256 + tid;
            const int ar = ec >> 3, d = ec & 7;
            const int ao = (d ^ (ar & 7)) << 3;
            async16(&A[(size_t)(row0 + ar) * 1024 + k0 + ao], &As[ec << 3]);
        }
#pragma unroll
        for (int r = 0; r < 2; ++r) {
            const int ec = r * 256 + tid;
            const int ar = ec >> 3, d = ec & 7;
            const int ao = (d ^ (ar & 7)) << 3;
            async16(&Bt[(size_t)(col0 + ar) * 1024 + k0 + ao], &Bl[ec << 3]);
            async16(&Bt[(size_t)(2048 + col0 + ar) * 1024 + k0 + ao], &Br[ec << 3]);
        }
        __syncthreads();
#pragma unroll
        for (int kk = 0; kk < 2; ++kk) {
            const int co = (((kk << 2) | quad) ^ s7) << 3;
            bf16x8 af[2], bl[4], br[4];
#pragma unroll
            for (int ii = 0; ii < 2; ++ii)
                af[ii] = *(const bf16x8*)&As[(wr + ii * 16 + l15) * 64 + co];
#pragma unroll
            for (int j = 0; j < 4; ++j) {
                bl[j] = *(const bf16x8*)&Bl[(j * 16 + l15) * 64 + co];
                br[j] = *(const bf16x8*)&Br[(j * 16 + l15) * 64 + co];
            }
#pragma unroll
            for (int ii = 0; ii < 2; ++ii)
#pragma unroll
                for (int j = 0; j < 4; ++j) {
                    accl[ii][j] = __builtin_amdgcn_mfma_f32_16x16x32_bf16(af[ii], bl[j], accl[ii][j], 0, 0, 0);
                    accr[ii][j] = __builtin_amdgcn_mfma_f32_16x16x32_bf16(af[ii], br[j], accr[ii][j], 0, 0, 0);
                }
        }
        __syncthreads();
    }

    const int r4 = quad * 4;
#pragma unroll
    for (int ii = 0; ii < 2; ++ii) {
#pragma unroll
        for (int j = 0; j < 4; ++j) {
#pragma unroll
            for (int rg = 0; rg < 4; ++rg) {
                const int orow = row0 + wr + ii * 16 + r4 + rg;
                const int ocol = col0 + j * 16 + l15;
                const float l = accl[ii][j][rg];
                const float r = accr[ii][j][rg];
                out[(size_t)orow * 2048 + ocol] =
                    __float2bfloat16(l * (1.f / (1.f + __expf(-r))));
            }
        }
    }
}

// ---------------------------------------------------------------------------
// MFMA flash attention v15 (r13/r14/r17 proven best, 4-wave): v12 skeleton +
// log2-domain softmax via RAW __builtin_amdgcn_exp2f.
// ---------------------------------------------------------------------------
#define KADV (64 * 3072)
#define SCL2E 0.1803368801f   // 0.125 * log2(e)
#define RESCALE_THR2 11.54f   // 8 * log2(e)

__global__ __launch_bounds__(256, 4) void flash_mfma(const __hip_bfloat16* __restrict__ qkv_,
                                                     const __hip_bfloat16* __restrict__ VT_,
                                                     const int* __restrict__ mask,
                                                     __hip_bfloat16* __restrict__ attnb) {
    const unsigned short* qkv = (const unsigned short*)qkv_;
    const unsigned short* VT = (const unsigned short*)VT_;
    __shared__ __align__(16) short Ks[2][64 * 64];  // [buf][key][dim], swizzled
    __shared__ __align__(16) short Vt[2][64 * 64];  // [buf][dim][key], swizzled
    __shared__ __align__(16) short Ps[4][16 * 64];  // per-wave P [q][k], swizzled

    const int tid = threadIdx.x;
    const int lane = tid & 63;
    const int wave = tid >> 6;
    const int l15 = lane & 15;
    const int quad = lane >> 4;
    const int s7 = l15 & 7;

    // XCD-aware decode + balanced qt bijection (per-CU totals = 66 units)
    const int xcd = blockIdx.x & 7;
    const int slot = blockIdx.x >> 3;
    const int bh = xcd + ((slot & 3) << 3);
    const int v = slot >> 2;                 // [0,32)
    const int vr = v & 7, vs = v >> 3;       // vs in [0,4)
    const int qt = (vs == 0) ? 31 - vr : (vs == 1) ? vr : (vs == 2) ? 23 - vr : 8 + vr;
    const int h = bh & 15;
    const int b = bh >> 4;
    const int q0 = qt * 64 + wave * 16;

    // hoisted per-thread staging pointers (chunk 0) + fixed LDS dests
    const int e0 = tid, e1 = 256 + tid;
    const int r0 = e0 >> 3, d0 = e0 & 7, r1 = e1 >> 3, d1 = e1 & 7;
    const unsigned short* kp0 = qkv + (size_t)(b * SS + r0) * 3072 + 1024 + h * 64 + ((d0 ^ (r0 & 7)) << 3);
    const unsigned short* kp1 = qkv + (size_t)(b * SS + r1) * 3072 + 1024 + h * 64 + ((d1 ^ (r1 & 7)) << 3);
    const unsigned short* vp0 = VT + (size_t)(h * 64 + r0) * 4096 + b * SS + ((d0 ^ (r0 & 7)) << 3);
    const unsigned short* vp1 = VT + (size_t)(h * 64 + r1) * 4096 + b * SS + ((d1 ^ (r1 & 7)) << 3);
    short* const kd0a = &Ks[0][e0 << 3]; short* const kd0b = &Ks[1][e0 << 3];
    short* const kd1a = &Ks[0][e1 << 3]; short* const kd1b = &Ks[1][e1 << 3];
    short* const vd0a = &Vt[0][e0 << 3]; short* const vd0b = &Vt[1][e0 << 3];
    short* const vd1a = &Vt[0][e1 << 3]; short* const vd1b = &Vt[1][e1 << 3];

    const int* const mrow = mask + b * SS;

    // Q fragments (B-operand: col=q=l15, elems d=ks*32+quad*8..)
    bf16x8 aq[2];
#pragma unroll
    for (int ks = 0; ks < 2; ++ks)
        aq[ks] = *(const bf16x8*)(qkv + (size_t)(b * SS + q0 + l15) * 3072 +
                                  h * 64 + ks * 32 + quad * 8);

    // O^T accumulators: [d-tile nt][rg]: d = nt*16+quad*4+rg, q = q0+l15
    f32x4 O[4];
#pragma unroll
    for (int i = 0; i < 4; ++i) O[i] = (f32x4){0.f, 0.f, 0.f, 0.f};
    float m_r = BIGNEG, l_r = 0.f;   // per-lane scalars, log2 domain

    short* const Pw = &Ps[wave][0];

    // stage chunk 0 into buffer 0; advance pointers to chunk 1
    async16(kp0, kd0a); async16(kp1, kd1a);
    async16(vp0, vd0a); async16(vp1, vd1a);
    kp0 += KADV; kp1 += KADV; vp0 += 64; vp1 += 64;

    // ======== FULL chunks 0..qt-1 (ktmax=ktfull=4 for every wave) ========
    for (int c = 0; c < qt; ++c) {
        const int cur = c & 1;
        __syncthreads();   // drains chunk-c DMA + chunk-(c-1) LDS reads

        // prefetch chunk c+1 into the other buffer (c+1 <= qt always valid)
        async16(kp0, cur ? kd0a : kd0b);
        async16(kp1, cur ? kd1a : kd1b);
        async16(vp0, cur ? vd0a : vd0b);
        async16(vp1, cur ? vd1a : vd1b);
        kp0 += KADV; kp1 += KADV; vp0 += 64; vp1 += 64;

        const int kb = c << 6;
        const short* Kc = &Ks[cur][0];
        const short* Vc = &Vt[cur][0];

        int4 mv[4];
#pragma unroll
        for (int kt = 0; kt < 4; ++kt)
            mv[kt] = *(const int4*)&mrow[kb + kt * 16 + quad * 4];

        // ---- S^T = K Q^T, straight-line
        f32x4 S[4];
        __builtin_amdgcn_s_setprio(1);
#pragma unroll
        for (int kt = 0; kt < 4; ++kt) {
            const bf16x8 bk0 = *(const bf16x8*)&Kc[(kt * 16 + l15) * 64 + ((quad ^ s7) << 3)];
            const bf16x8 bk1 = *(const bf16x8*)&Kc[(kt * 16 + l15) * 64 + (((4 | quad) ^ s7) << 3)];
            f32x4 z = {0.f, 0.f, 0.f, 0.f};
            z = __builtin_amdgcn_mfma_f32_16x16x32_bf16(bk0, aq[0], z, 0, 0, 0);
            S[kt] = __builtin_amdgcn_mfma_f32_16x16x32_bf16(bk1, aq[1], z, 0, 0, 0);
        }
        __builtin_amdgcn_s_setprio(0);

        // ---- scale (log2 domain) + mask-bias (no causal below the diagonal)
#pragma unroll
        for (int kt = 0; kt < 4; ++kt) {
            const int* mm = (const int*)&mv[kt];
#pragma unroll
            for (int rg = 0; rg < 4; ++rg)
                S[kt][rg] = fmaf(S[kt][rg], SCL2E, mm[rg] ? 0.f : BIGNEG);
        }

        // ---- row max: in-lane tree (16) + cross-quad shfl(16,32)
        const float t0 = fmaxf(fmaxf(S[0][0], S[0][1]), fmaxf(S[0][2], S[0][3]));
        const float t1 = fmaxf(fmaxf(S[1][0], S[1][1]), fmaxf(S[1][2], S[1][3]));
        const float t2 = fmaxf(fmaxf(S[2][0], S[2][1]), fmaxf(S[2][2], S[2][3]));
        const float t3 = fmaxf(fmaxf(S[3][0], S[3][1]), fmaxf(S[3][2], S[3][3]));
        float tmax = fmaxf(fmaxf(t0, t1), fmaxf(t2, t3));
        tmax = fmaxf(tmax, __shfl_xor(tmax, 16));
        tmax = fmaxf(tmax, __shfl_xor(tmax, 32));

        // T13 defer-max (log2 domain)
        if (__any(tmax > m_r + RESCALE_THR2)) {
            const float mn = fmaxf(m_r, tmax);
            const float alpha = fast_exp2(m_r - mn);
            m_r = mn;
            l_r *= alpha;
#pragma unroll
            for (int nt = 0; nt < 4; ++nt)
#pragma unroll
                for (int rg = 0; rg < 4; ++rg)
                    O[nt][rg] *= alpha;
        }

        // ---- P = exp2(S - m), row-sum, pack to b64
        float rsum = 0.f;
        unsigned long long p64[4];
#pragma unroll
        for (int kt = 0; kt < 4; ++kt) {
#pragma unroll
            for (int rg = 0; rg < 4; ++rg)
                S[kt][rg] = fast_exp2(S[kt][rg] - m_r);
            rsum += (S[kt][0] + S[kt][1]) + (S[kt][2] + S[kt][3]);
            p64[kt] = ((unsigned long long)(((unsigned)f2bu(S[kt][3]) << 16) | f2bu(S[kt][2])) << 32)
                    | (((unsigned)f2bu(S[kt][1]) << 16) | f2bu(S[kt][0]));
        }
        rsum += __shfl_xor(rsum, 16);
        rsum += __shfl_xor(rsum, 32);
        l_r += rsum;

        // ---- P -> LDS: 4x ds_write_b64 (all 32 banks, balanced)
#pragma unroll
        for (int kt = 0; kt < 4; ++kt) {
            const int ch = (kt << 1) | (quad >> 1);
            const int base = (l15 << 6) + ((ch ^ s7) << 3) + ((quad & 1) << 2);
            *(unsigned long long*)&Pw[base] = p64[kt];
        }

        // ---- O^T += V_frag * P_frag
        __builtin_amdgcn_s_setprio(1);
#pragma unroll
        for (int kk = 0; kk < 2; ++kk) {
            const int co = ((((kk << 2) | quad) ^ s7) << 3);
            const bf16x8 bp = *(const bf16x8*)&Pw[(l15 << 6) + co];
#pragma unroll
            for (int nt = 0; nt < 4; ++nt) {
                const bf16x8 av = *(const bf16x8*)&Vc[(nt * 16 + l15) * 64 + co];
                O[nt] = __builtin_amdgcn_mfma_f32_16x16x32_bf16(av, bp, O[nt], 0, 0, 0);
            }
        }
        __builtin_amdgcn_s_setprio(0);
    }

    // ======== DIAGONAL chunk c = qt (dynamic per-wave extent) ========
    {
        const int cur = qt & 1;
        __syncthreads();

        const int kb = qt << 6;
        const int ktmax = wave + 1;     // dq = wave*16
        const int ktfull = wave;        // only tile kt==wave is partial
        const short* Kc = &Ks[cur][0];
        const short* Vc = &Vt[cur][0];
        const int qrow = q0 + l15;

        int4 mv[4];
#pragma unroll
        for (int kt = 0; kt < 4; ++kt) {
            if (kt >= ktmax) break;
            mv[kt] = *(const int4*)&mrow[kb + kt * 16 + quad * 4];
        }

        f32x4 S[4];
        __builtin_amdgcn_s_setprio(1);
#pragma unroll
        for (int kt = 0; kt < 4; ++kt) {
            if (kt >= ktmax) break;
            const bf16x8 bk0 = *(const bf16x8*)&Kc[(kt * 16 + l15) * 64 + ((quad ^ s7) << 3)];
            const bf16x8 bk1 = *(const bf16x8*)&Kc[(kt * 16 + l15) * 64 + (((4 | quad) ^ s7) << 3)];
            f32x4 z = {0.f, 0.f, 0.f, 0.f};
            z = __builtin_amdgcn_mfma_f32_16x16x32_bf16(bk0, aq[0], z, 0, 0, 0);
            S[kt] = __builtin_amdgcn_mfma_f32_16x16x32_bf16(bk1, aq[1], z, 0, 0, 0);
        }
        __builtin_amdgcn_s_setprio(0);

#pragma unroll
        for (int kt = 0; kt < 4; ++kt) {
            if (kt >= ktmax) break;
            const int* mm = (const int*)&mv[kt];
#pragma unroll
            for (int rg = 0; rg < 4; ++rg) {
                float s = fmaf(S[kt][rg], SCL2E, mm[rg] ? 0.f : BIGNEG);
                if (kt >= ktfull) {
                    const int key = kb + kt * 16 + quad * 4 + rg;
                    s = (key <= qrow) ? s : BIGNEG;
                }
                S[kt][rg] = s;
            }
        }

        float tmax = BIGNEG;
#pragma unroll
        for (int kt = 0; kt < 4; ++kt) {
            if (kt >= ktmax) break;
            tmax = fmaxf(tmax, fmaxf(fmaxf(S[kt][0], S[kt][1]),
                                     fmaxf(S[kt][2], S[kt][3])));
        }
        tmax = fmaxf(tmax, __shfl_xor(tmax, 16));
        tmax = fmaxf(tmax, __shfl_xor(tmax, 32));

        if (__any(tmax > m_r + RESCALE_THR2)) {
            const float mn = fmaxf(m_r, tmax);
            const float alpha = fast_exp2(m_r - mn);
            m_r = mn;
            l_r *= alpha;
#pragma unroll
            for (int nt = 0; nt < 4; ++nt)
#pragma unroll
                for (int rg = 0; rg < 4; ++rg)
                    O[nt][rg] *= alpha;
        }

        float rsum = 0.f;
#pragma unroll
        for (int kt = 0; kt < 4; ++kt) {
            if (kt >= ktmax) break;
#pragma unroll
            for (int rg = 0; rg < 4; ++rg)
                S[kt][rg] = fast_exp2(S[kt][rg] - m_r);
            rsum += (S[kt][0] + S[kt][1]) + (S[kt][2] + S[kt][3]);
            const int ch = (kt << 1) | (quad >> 1);
            const int base = (l15 << 6) + ((ch ^ s7) << 3) + ((quad & 1) << 2);
            *(unsigned long long*)&Pw[base] =
                ((unsigned long long)(((unsigned)f2bu(S[kt][3]) << 16) | f2bu(S[kt][2])) << 32)
                | (((unsigned)f2bu(S[kt][1]) << 16) | f2bu(S[kt][0]));
        }
        rsum += __shfl_xor(rsum, 16);
        rsum += __shfl_xor(rsum, 32);
        l_r += rsum;

        const int kkmax = (ktmax + 1) >> 1;
        if (ktmax & 1) {   // zero-fill phantom tile
            const int ch = (ktmax << 1) | (quad >> 1);
            const int base = (l15 << 6) + ((ch ^ s7) << 3) + ((quad & 1) << 2);
            *(unsigned long long*)&Pw[base] = 0ull;
        }

        __builtin_amdgcn_s_setprio(1);
#pragma unroll
        for (int kk = 0; kk < 2; ++kk) {
            if (kk >= kkmax) break;
            const int co = ((((kk << 2) | quad) ^ s7) << 3);
            const bf16x8 bp = *(const bf16x8*)&Pw[(l15 << 6) + co];
#pragma unroll
            for (int nt = 0; nt < 4; ++nt) {
                const bf16x8 av = *(const bf16x8*)&Vc[(nt * 16 + l15) * 64 + co];
                O[nt] = __builtin_amdgcn_mfma_f32_16x16x32_bf16(av, bp, O[nt], 0, 0, 0);
            }
        }
        __builtin_amdgcn_s_setprio(0);
    }

    // epilogue: O^T /= l, write bf16. Lane owns row q = q0+l15,
    // d = nt*16 + quad*4 + rg -> 4x 8-byte stores.
    const float inv = 1.f / l_r;
    unsigned short* op = (unsigned short*)attnb +
                         (size_t)(b * SS + q0 + l15) * 1024 + h * 64 + quad * 4;
#pragma unroll
    for (int nt = 0; nt < 4; ++nt) {
        const float o0 = O[nt][0] * inv, o1 = O[nt][1] * inv;
        const float o2 = O[nt][2] * inv, o3 = O[nt][3] * inv;
        const unsigned long long pk =
            (unsigned long long)(((unsigned)f2bu(o3) << 16) | f2bu(o2)) << 32 |
            (((unsigned)f2bu(o1) << 16) | f2bu(o0));
        *(unsigned long long*)(op + nt * 16) = pk;
    }
}

// ---------------------------------------------------------------------------
// Launch (r17 converged config, 187.7us). Workspace plan (84 MB peak), bytes:
//   [0,6M)   Wqkv_t bf16 [3072][1024]
//   [6,8M)   Wo_t   bf16 [1024][1024]
//   [8,16M)  W1_t   bf16 [4096][1024]  (plain transposed)
//   [16,20M) W2_t   bf16 [1024][2048]
//   [20,28M) lnb    bf16 (ln1 then ln2)
//   [28,52M) qkvb   bf16 [4096][3072]  (V cols unwritten) -> dead after flash
//   [28,44M) x1     fp32 (reuses qkvb head)
//   [52,60M) attnb  bf16               -> dead after Wo gemm
//   [60,68M) VT     bf16 [1024][4096]  (written by qkv GEMM) -> dead after flash
//   [68,84M) glub   bf16 [4096][2048]
// ---------------------------------------------------------------------------
extern "C" void kernel_launch(void* const* d_in, const int* in_sizes, int n_in,
                              void* d_out, int out_size, void* d_ws, size_t ws_size,
                              hipStream_t stream) {
    const float* x  = (const float*)d_in[0];
    const int* mask = (const int*)d_in[1];
    const float* Wq = (const float*)d_in[2];
    const float* Wk = (const float*)d_in[3];
    const float* Wv = (const float*)d_in[4];
    const float* Wo = (const float*)d_in[5];
    const float* W1 = (const float*)d_in[6];
    const float* W2 = (const float*)d_in[7];
    const float* g1 = (const float*)d_in[8];
    const float* b1 = (const float*)d_in[9];
    const float* g2 = (const float*)d_in[10];
    const float* b2 = (const float*)d_in[11];

    const size_t MB = 1024 * 1024;
    uint8_t* ws = (uint8_t*)d_ws;
    __hip_bfloat16* wqkvt = (__hip_bfloat16*)(ws);
    __hip_bfloat16* wot   = (__hip_bfloat16*)(ws + 6 * MB);
    __hip_bfloat16* w1t   = (__hip_bfloat16*)(ws + 8 * MB);
    __hip_bfloat16* w2t   = (__hip_bfloat16*)(ws + 16 * MB);
    __hip_bfloat16* lnb   = (__hip_bfloat16*)(ws + 20 * MB);
    __hip_bfloat16* qkvb  = (__hip_bfloat16*)(ws + 28 * MB);
    float*          x1    = (float*)(ws + 28 * MB);
    __hip_bfloat16* attnb = (__hip_bfloat16*)(ws + 52 * MB);
    __hip_bfloat16* VT    = (__hip_bfloat16*)(ws + 60 * MB);
    __hip_bfloat16* glub  = (__hip_bfloat16*)(ws + 68 * MB);

    // 0. weight transposes + ln1 in one launch
    prep_kernel<<<10240 + NTOK, 256, 0, stream>>>(Wq, Wk, Wv, Wo, W1, W2,
                                                  wqkvt, wot, w1t, w2t,
                                                  x, g1, b1, lnb);

    // 1. qkv = ln1 @ [Wq|Wk|Wv]. Q,K -> qkvb rows; V cols -> VT transposed.
    mfma_gemm<0, 1><<<768, 256, 0, stream>>>(lnb, wqkvt, nullptr, qkvb,
                                             NTOK, 3072, 1024, 12, 2, VT);

    // 2. MFMA flash attention -> attnb  [4-wave, 1024 blocks = 4/CU]
    flash_mfma<<<1024, 256, 0, stream>>>(qkvb, VT, mask, attnb);

    // 3. x1 = x + attn @ Wo -> x1 (fp32)  [64x64, 1024 blocks = 4/CU]
    mfma_gemm_n6464<1, 0><<<1024, 256, 0, stream>>>(attnb, wot, x, x1, 1024, 1024);

    // 4. ln2 = LN(x1) -> lnb
    ln_kernel<<<NTOK, 256, 0, stream>>>(x1, g2, b2, lnb);

    // 5. glu = (ln2@W1L) * sigmoid(ln2@W1R) -> glub
    //    [128x64, 1024 blocks = 4/CU, 2D XCD chunks of 8 rows x 16 cols]
    mfma_gemm_glu64<<<1024, 256, 0, stream>>>(lnb, w1t, glub);

    // 6. out = x1 + glu @ W2 -> d_out (fp32)  [64x64, 1024 blocks = 4/CU]
    mfma_gemm_n6464<1, 0><<<1024, 256, 0, stream>>>(glub, w2t, x1, (float*)d_out,
                                                    1024, 2048);
}